// Round 3
// baseline (216.805 us; speedup 1.0000x reference)
//
#include <hip/hip_runtime.h>
#include <math.h>

#define BN_ 16
#define SS  2048
#define HH  1024
#define AA  64

typedef unsigned short u16;
typedef __bf16 bf16x8 __attribute__((ext_vector_type(8)));
typedef float  f32x4  __attribute__((ext_vector_type(4)));
#define MFMA16 __builtin_amdgcn_mfma_f32_16x16x32_bf16

// ---------------- ws layout (float offsets) ----------------
#define QK_OFF    0
#define QK_FLOATS (BN_*SS*64)           // bf16 qk[32768][128]: Q cols 0..63, K cols 64..127
#define WT_OFF    (QK_OFF + QK_FLOATS)  // bf16 wt[128][1024] (WqT||WkT)
#define WT_FLOATS (64*HH)
#define CP_OFF    (WT_OFF + WT_FLOATS)  // cpart[16][32][2][2048] fp32 (strip col partials)
#define CP_FLOATS (BN_*32*2*SS)
#define W_OFF     (CP_OFF + CP_FLOATS)  // w[b][t]
#define NB_OFF    (W_OFF + BN_*SS)      // Nb per batch [16]
#define WSUM_OFF  (NB_OFF + 16)         // sum of w per batch [16]
#define UP_OFF    (WSUM_OFF + 16)       // u_part[16][32][1024] fp32

__device__ __forceinline__ u16 f2b(float f) {
    unsigned u = __builtin_bit_cast(unsigned, f);
    return (u16)((u + 0x7FFFu + ((u >> 16) & 1u)) >> 16);
}

// swizzled elem index in a [rows][64] bf16 LDS tile (row stride 128B)
__device__ __forceinline__ int swze(int row, int e) {
    return row * 64 + (e ^ ((row & 7) << 3));
}

// MFMA A/B fragment from swizzled tile: rows row16..row16+15, k-step ks
__device__ __forceinline__ bf16x8 ldfrag(const u16* t, int row16, int ks, int l6) {
    int row = row16 + (l6 & 15);
    int e = ks * 32 + ((l6 >> 4) << 3);
    return *(const bf16x8*)&t[swze(row, e)];
}

// stage a [128][64]-bf16 tile from global (row stride gstride u16)
__device__ __forceinline__ void stage_bf16(u16* dst, const u16* __restrict__ src,
                                           int gstride, int tid) {
    int r = tid >> 3, c8 = tid & 7;
    #pragma unroll
    for (int pass = 0; pass < 4; ++pass) {
        int rr = r + pass * 32;
        uint4 v = *(const uint4*)&src[(size_t)rr * gstride + c8 * 8];
        *(uint4*)&dst[swze(rr, c8 * 8)] = v;
    }
}

// stage a [64][64]-bf16 tile from qk (row stride 128 u16)
__device__ __forceinline__ void stage64(u16* dst, const u16* __restrict__ src, int tid) {
    int r = tid >> 3, c8 = tid & 7;
    #pragma unroll
    for (int pass = 0; pass < 2; ++pass) {
        int rr = r + pass * 32;
        uint4 v = *(const uint4*)&src[(size_t)rr * 128 + c8 * 8];
        *(uint4*)&dst[swze(rr, c8 * 8)] = v;
    }
}

// ---- A: transpose Wq||Wk -> bf16 wt[128][1024] ----
__global__ __launch_bounds__(256) void k_wt(const float* __restrict__ Wq,
                                            const float* __restrict__ Wk,
                                            u16* __restrict__ wt) {
    int n = blockIdx.x;
    const float* src = (n < 64) ? &Wq[n] : &Wk[n - 64];
    for (int k = threadIdx.x; k < HH; k += 256)
        wt[(size_t)n * HH + k] = f2b(src[(size_t)k * AA]);
}

// ---- B: QK projection via MFMA, M-tile 64 (512 blocks) ----
__global__ __launch_bounds__(256) void k_qkproj(const float* __restrict__ x,
                                                const u16* __restrict__ wt,
                                                const float* __restrict__ bq,
                                                const float* __restrict__ bk,
                                                u16* __restrict__ qk) {
    __shared__ __align__(16) u16 At[64 * 64];
    __shared__ __align__(16) u16 Bt[128 * 64];
    int tid = threadIdx.x, l6 = tid & 63, w = tid >> 6;
    int m0 = blockIdx.x * 64;
    const f32x4 vz = {0.f, 0.f, 0.f, 0.f};
    f32x4 acc[8];
    #pragma unroll
    for (int j = 0; j < 8; ++j) acc[j] = vz;

    for (int kt = 0; kt < 16; ++kt) {
        __syncthreads();
        {   // stage A: x fp32 -> bf16 swizzled (64x64)
            int r = tid >> 2, c0 = (tid & 3) * 16;
            #pragma unroll
            for (int k = 0; k < 4; ++k) {
                float4 v = *(const float4*)&x[(size_t)(m0 + r) * HH + kt * 64 + c0 + 4 * k];
                ushort4 h;
                h.x = f2b(v.x); h.y = f2b(v.y); h.z = f2b(v.z); h.w = f2b(v.w);
                *(ushort4*)&At[swze(r, c0 + 4 * k)] = h;
            }
            stage_bf16(Bt, &wt[kt * 64], HH, tid);
        }
        __syncthreads();
        bf16x8 a0 = ldfrag(At, w * 16, 0, l6);
        bf16x8 a1 = ldfrag(At, w * 16, 1, l6);
        #pragma unroll
        for (int j = 0; j < 8; ++j) {
            acc[j] = MFMA16(a0, ldfrag(Bt, j * 16, 0, l6), acc[j], 0, 0, 0);
            acc[j] = MFMA16(a1, ldfrag(Bt, j * 16, 1, l6), acc[j], 0, 0, 0);
        }
    }
    #pragma unroll
    for (int j = 0; j < 8; ++j) {
        int n = j * 16 + (l6 & 15);
        float bias = (n < 64) ? bq[n] : bk[n - 64];
        int mrow = m0 + w * 16 + ((l6 >> 4) << 2);
        #pragma unroll
        for (int r4 = 0; r4 < 4; ++r4)
            qk[(size_t)(mrow + r4) * 128 + n] = f2b(acc[j][r4] + bias);
    }
}

// ---- E: Nb per batch ----
__global__ __launch_bounds__(256) void k_nb(const int* __restrict__ mask,
                                            float* __restrict__ nbv) {
    int b = blockIdx.x, tid = threadIdx.x;
    int s = 0;
    for (int i = tid; i < SS; i += 256) s += mask[b * SS + i];
    float fs = (float)s;
    for (int off = 1; off < 64; off <<= 1) fs += __shfl_xor(fs, off);
    __shared__ float red[4];
    if ((tid & 63) == 0) red[tid >> 6] = fs;
    __syncthreads();
    if (tid == 0) nbv[b] = red[0] + red[1] + red[2] + red[3] + 1e-8f;
}

// ---- C+D fused: strip = 64 s-rows; pass1 -> l in regs; pass2 -> col partials ----
__global__ __launch_bounds__(256) void k_score(const u16* __restrict__ qk,
                                               const int* __restrict__ mask,
                                               float* __restrict__ cpart) {
    __shared__ __align__(16) u16 Qs[64 * 64];
    __shared__ __align__(16) u16 Ks[128 * 64];
    __shared__ float pmsh[SS];
    __shared__ float redbuf[4][2][128];
    int b = blockIdx.x, sb = blockIdx.y;     // sb 0..31
    int tid = threadIdx.x, l6 = tid & 63, w = tid >> 6;
    for (int i = tid; i < SS; i += 256) pmsh[i] = mask[b * SS + i] ? 1.f : 0.f;
    stage64(Qs, qk + (size_t)(b * SS + sb * 64) * 128, tid);
    __syncthreads();
    bf16x8 q0 = ldfrag(Qs, w * 16, 0, l6);
    bf16x8 q1 = ldfrag(Qs, w * 16, 1, l6);
    const f32x4 vz = {0.f, 0.f, 0.f, 0.f};
    float rsum[4] = {};
    // ---- pass 1: row sums ----
    for (int tt = 0; tt < 16; ++tt) {
        __syncthreads();
        stage_bf16(Ks, qk + (size_t)(b * SS + tt * 128) * 128 + 64, 128, tid);
        __syncthreads();
        #pragma unroll
        for (int j = 0; j < 8; ++j) {
            f32x4 a = vz;
            a = MFMA16(q0, ldfrag(Ks, j * 16, 0, l6), a, 0, 0, 0);
            a = MFMA16(q1, ldfrag(Ks, j * 16, 1, l6), a, 0, 0, 0);
            float pm = pmsh[tt * 128 + j * 16 + (l6 & 15)];
            #pragma unroll
            for (int r4 = 0; r4 < 4; ++r4)
                rsum[r4] += pm * __expf(a[r4] * 0.125f);
        }
    }
    #pragma unroll
    for (int off = 1; off < 16; off <<= 1)
        #pragma unroll
        for (int r4 = 0; r4 < 4; ++r4) rsum[r4] += __shfl_xor(rsum[r4], off);
    float invl[4], qmr[4];
    int rbase = sb * 64 + w * 16 + ((l6 >> 4) << 2);
    #pragma unroll
    for (int r4 = 0; r4 < 4; ++r4) {
        float lv = rsum[r4];
        float inv = (lv > 0.f) ? 1.f / lv : 0.f;
        invl[r4] = inv;
        qmr[r4] = pmsh[rbase + r4] * inv;
    }
    // ---- pass 2: column partials ----
    for (int tt = 0; tt < 16; ++tt) {
        __syncthreads();   // protects Ks and redbuf
        stage_bf16(Ks, qk + (size_t)(b * SS + tt * 128) * 128 + 64, 128, tid);
        __syncthreads();
        #pragma unroll
        for (int j = 0; j < 8; ++j) {
            f32x4 a = vz;
            a = MFMA16(q0, ldfrag(Ks, j * 16, 0, l6), a, 0, 0, 0);
            a = MFMA16(q1, ldfrag(Ks, j * 16, 1, l6), a, 0, 0, 0);
            float sa = 0.f, sm = 0.f;
            #pragma unroll
            for (int r4 = 0; r4 < 4; ++r4) {
                float e = __expf(a[r4] * 0.125f);
                sa += e * invl[r4];
                sm += e * qmr[r4];
            }
            sa += __shfl_xor(sa, 16); sa += __shfl_xor(sa, 32);
            sm += __shfl_xor(sm, 16); sm += __shfl_xor(sm, 32);
            if (l6 < 16) {
                redbuf[w][0][j * 16 + l6] = sa;
                redbuf[w][1][j * 16 + l6] = sm;
            }
        }
        __syncthreads();
        int a2 = tid >> 7, tl = tid & 127;
        float s = redbuf[0][a2][tl] + redbuf[1][a2][tl]
                + redbuf[2][a2][tl] + redbuf[3][a2][tl];
        cpart[(((size_t)b * 32 + sb) * 2 + a2) * SS + tt * 128 + tl] = s;
    }
}

// ---- F: reduce col partials -> attn_mean, w, wsum ----
__global__ __launch_bounds__(256) void k_finalize(const float* __restrict__ cpart,
                                                  const int* __restrict__ mask,
                                                  const float* __restrict__ nbv,
                                                  float* __restrict__ w,
                                                  float* __restrict__ wsum,
                                                  float* __restrict__ out_mean) {
    int b = blockIdx.x, tid = threadIdx.x;
    float inv_nb = 1.f / nbv[b];
    float wacc = 0.f;
    for (int it = 0; it < 8; ++it) {
        int t = it * 256 + tid;
        float sa = 0.f, sm = 0.f;
        #pragma unroll 8
        for (int k = 0; k < 32; ++k) {
            const float* p = &cpart[(((size_t)b * 32 + k) * 2) * SS + t];
            sa += p[0];
            sm += p[SS];
        }
        float pm = mask[b * SS + t] ? 1.f : 0.f;
        out_mean[b * SS + t] = sa * pm * (1.f / SS);
        float wv = sm * pm * inv_nb;
        w[b * SS + t] = wv;
        wacc += wv;
    }
    for (int off = 1; off < 64; off <<= 1) wacc += __shfl_xor(wacc, off);
    __shared__ float red[4];
    if ((tid & 63) == 0) red[tid >> 6] = wacc;
    __syncthreads();
    if (tid == 0) wsum[b] = red[0] + red[1] + red[2] + red[3];
}

// ---- G: u partials: u_part[b][ch][c] = sum_{t in chunk} w[t]*x[t][c] ----
__global__ __launch_bounds__(256) void k_u(const float* __restrict__ x,
                                           const float* __restrict__ w,
                                           float* __restrict__ u_part) {
    __shared__ float wl[64];
    int b = blockIdx.x, ch = blockIdx.y;   // ch 0..31, 64 t each
    int tid = threadIdx.x;
    if (tid < 64) wl[tid] = w[b * SS + ch * 64 + tid];
    __syncthreads();
    const float* xb = &x[((size_t)b * SS + ch * 64) * HH + tid * 4];
    float4 acc = {0.f, 0.f, 0.f, 0.f};
    #pragma unroll 8
    for (int t = 0; t < 64; ++t) {
        float4 xv = *(const float4*)&xb[(size_t)t * HH];
        float wv = wl[t];
        acc.x += wv * xv.x; acc.y += wv * xv.y;
        acc.z += wv * xv.z; acc.w += wv * xv.w;
    }
    *(float4*)&u_part[((size_t)b * 32 + ch) * HH + tid * 4] = acc;
}

// ---- H: out0[b][h] = sum_c u[b][c]*Wv[c][h] + bv[h]*wsum[b] ----
__global__ __launch_bounds__(256) void k_out0(const float* __restrict__ u_part,
                                              const float* __restrict__ Wv,
                                              const float* __restrict__ bv,
                                              const float* __restrict__ wsum,
                                              float* __restrict__ out) {
    __shared__ float us[HH];
    int b = blockIdx.x, hb = blockIdx.y;
    int tid = threadIdx.x;
    float4 s = {0.f, 0.f, 0.f, 0.f};
    #pragma unroll 8
    for (int ch = 0; ch < 32; ++ch) {
        float4 v = *(const float4*)&u_part[((size_t)b * 32 + ch) * HH + tid * 4];
        s.x += v.x; s.y += v.y; s.z += v.z; s.w += v.w;
    }
    *(float4*)&us[tid * 4] = s;
    __syncthreads();
    int h = hb * 256 + tid;
    float acc = bv[h] * wsum[b];
    #pragma unroll 8
    for (int c = 0; c < HH; ++c)
        acc += us[c] * Wv[(size_t)c * HH + h];
    out[b * HH + h] = acc;
}

extern "C" void kernel_launch(void* const* d_in, const int* in_sizes, int n_in,
                              void* d_out, int out_size, void* d_ws, size_t ws_size,
                              hipStream_t stream) {
    const float* x  = (const float*)d_in[0];
    const int* mask = (const int*)d_in[1];
    const float* Wq = (const float*)d_in[2];
    const float* bq = (const float*)d_in[3];
    const float* Wk = (const float*)d_in[4];
    const float* bk = (const float*)d_in[5];
    const float* Wv = (const float*)d_in[6];
    const float* bv = (const float*)d_in[7];
    float* out = (float*)d_out;
    float* ws  = (float*)d_ws;

    u16*   qk    = (u16*)(ws + QK_OFF);
    u16*   wt    = (u16*)(ws + WT_OFF);
    float* cpart = ws + CP_OFF;
    float* w     = ws + W_OFF;
    float* nbv   = ws + NB_OFF;
    float* wsum  = ws + WSUM_OFF;
    float* upart = ws + UP_OFF;

    // no memsets: every ws buffer is fully written before read (direct stores only)
    k_wt      <<<dim3(128),     dim3(256), 0, stream>>>(Wq, Wk, wt);
    k_qkproj  <<<dim3(512),     dim3(256), 0, stream>>>(x, wt, bq, bk, qk);
    k_nb      <<<dim3(BN_),     dim3(256), 0, stream>>>(mask, nbv);
    k_score   <<<dim3(BN_, 32), dim3(256), 0, stream>>>(qk, mask, cpart);
    k_finalize<<<dim3(BN_),     dim3(256), 0, stream>>>(cpart, mask, nbv, w, wsum, out + BN_ * HH);
    k_u       <<<dim3(BN_, 32), dim3(256), 0, stream>>>(x, w, upart);
    k_out0    <<<dim3(BN_, 4),  dim3(256), 0, stream>>>(upart, Wv, bv, wsum, out);
}